// Round 8
// baseline (1413.922 us; speedup 1.0000x reference)
//
#include <hip/hip_runtime.h>

typedef __attribute__((ext_vector_type(8))) short bf16x8;
typedef __attribute__((ext_vector_type(4))) float f32x4;
typedef __attribute__((ext_vector_type(4))) unsigned short u16x4;
typedef __attribute__((ext_vector_type(4))) unsigned u32x4;

#define CH2 4096         // t-chunk per sort block
#define MAXNT 1568       // max row-tiles supported by LDS hist
#define MAXG  32         // max k-groups supported by sort2 LDS bins

__device__ __forceinline__ unsigned short f2b(float f) {
    unsigned u = __builtin_bit_cast(unsigned, f);
    u += 0x7fffu + ((u >> 16) & 1u);   // round-to-nearest-even
    return (unsigned short)(u >> 16);
}

__global__ void zero_f32(float* __restrict__ p, long total) {
    long i = ((long)blockIdx.x * blockDim.x + threadIdx.x) * 4;
    if (i + 3 < total) {
        *(f32x4*)(p + i) = (f32x4){0.f, 0.f, 0.f, 0.f};
    } else {
        for (long t = i; t < total; ++t) p[t] = 0.f;
    }
}

__global__ void cvt_bf16(const float* __restrict__ x, unsigned short* __restrict__ o, long total) {
    long i = ((long)blockIdx.x * blockDim.x + threadIdx.x) * 4;
    if (i >= total) return;
    f32x4 v = *(const f32x4*)(x + i);
    u16x4 r;
#pragma unroll
    for (int t = 0; t < 4; ++t) r[t] = f2b(v[t]);
    *(u16x4*)(o + i) = r;
}

// Wb[k][frag f=kk*8+c][lane][j] = W[k][cin=kk*32+(lane>>4)*8+j][cout=c*16+(lane&15)]
__global__ void prep_w(const float* __restrict__ W1, const float* __restrict__ W2,
                       unsigned short* __restrict__ Wb1, unsigned short* __restrict__ Wb2,
                       int kelems) {
    int tid = blockIdx.x * 256 + threadIdx.x;
    if (tid >= 2 * kelems) return;
    int which = (tid >= kelems) ? 1 : 0;
    int rem = which ? (tid - kelems) : tid;
    int k = rem >> 14;
    int r2 = rem & 16383;
    int f = r2 >> 9;
    int lane = (r2 >> 3) & 63;
    int j = r2 & 7;
    int kk = f >> 3, c = f & 7;
    int cin = kk * 32 + (lane >> 4) * 8 + j;
    int cout = c * 16 + (lane & 15);
    const float* W = which ? W2 : W1;
    unsigned short* Wb = which ? Wb2 : Wb1;
    Wb[rem] = f2b(W[(size_t)k * 16384 + cin * 128 + cout]);
}

// ---------------- CSR build, all ranking via LDS atomics ----------------
// Sort 1: group contributions by row-tile. bins b = rt*NCH + chunk.

__global__ void pass_hist_t(const int* __restrict__ io, int* __restrict__ cnt,
                            int nk, int NT, int NCH) {
    __shared__ int hist[MAXNT];
    const int c = blockIdx.x;
    for (int i = threadIdx.x; i < NT; i += 256) hist[i] = 0;
    __syncthreads();
    const int t1 = min(nk, (c + 1) * CH2);
    for (int t = c * CH2 + threadIdx.x; t < t1; t += 256)
        atomicAdd(&hist[((unsigned)io[t]) >> 6], 1);
    __syncthreads();
    for (int rt = threadIdx.x; rt < NT; rt += 256)
        cnt[(size_t)rt * NCH + c] = hist[rt];
}

__global__ void scan_part(const int* __restrict__ cnt, int* __restrict__ bsum, int nbins) {
    __shared__ int ls[256];
    int base = blockIdx.x * 4096 + threadIdx.x * 16;
    int s = 0;
#pragma unroll
    for (int i = 0; i < 16; ++i) { int idx = base + i; if (idx < nbins) s += cnt[idx]; }
    ls[threadIdx.x] = s; __syncthreads();
    for (int o = 128; o > 0; o >>= 1) {
        if ((int)threadIdx.x < o) ls[threadIdx.x] += ls[threadIdx.x + o];
        __syncthreads();
    }
    if (threadIdx.x == 0) bsum[blockIdx.x] = ls[0];
}

__global__ void scan_bsum(int* __restrict__ bsum, int nb, int* __restrict__ sptr, int nbins) {
    if (threadIdx.x == 0 && blockIdx.x == 0) {
        int run = 0;
        for (int i = 0; i < nb; ++i) { int t = bsum[i]; bsum[i] = run; run += t; }
        sptr[nbins] = run;
    }
}

__global__ void scan_final(const int* __restrict__ cnt, const int* __restrict__ bsum,
                           int* __restrict__ sptr, int nbins) {
    __shared__ int ls[256];
    const int tid = threadIdx.x;
    int base = blockIdx.x * 4096 + tid * 16;
    int loc[16];
    int s = 0;
#pragma unroll
    for (int i = 0; i < 16; ++i) {
        int idx = base + i;
        int v = (idx < nbins) ? cnt[idx] : 0;
        loc[i] = s; s += v;
    }
    ls[tid] = s; __syncthreads();
    for (int o = 1; o < 256; o <<= 1) {
        int add = (tid >= o) ? ls[tid - o] : 0;
        __syncthreads();
        ls[tid] += add;
        __syncthreads();
    }
    int excl = ls[tid] - s + bsum[blockIdx.x];
#pragma unroll
    for (int i = 0; i < 16; ++i) {
        int idx = base + i;
        if (idx < nbins) sptr[idx] = excl + loc[i];
    }
}

// pay[p] = (t << 6) | (row & 63), grouped by row-tile (rank via LDS atomics)
__global__ void pass_scatter_t(const int* __restrict__ io, const int* __restrict__ sptr,
                               unsigned* __restrict__ pay, int nk, int NT, int NCH) {
    __shared__ int base[MAXNT];
    const int c = blockIdx.x;
    for (int rt = threadIdx.x; rt < NT; rt += 256)
        base[rt] = sptr[(size_t)rt * NCH + c];
    __syncthreads();
    const int t1 = min(nk, (c + 1) * CH2);
    for (int t = c * CH2 + threadIdx.x; t < t1; t += 256) {
        int r = io[t];
        int p = atomicAdd(&base[r >> 6], 1);
        pay[p] = ((unsigned)t << 6) | (unsigned)(r & 63);
    }
}

// Sort 2 (per tile): bin by row*G + group -> pay2 (= t) in exact (row,group)-CSR
// order + rp3[r*G+g] boundaries.
__global__ __launch_bounds__(256) void sort2_tile_g(
    const unsigned* __restrict__ pay, const int* __restrict__ sptr,
    unsigned* __restrict__ pay2, int* __restrict__ rp3,
    int n, int NCH, int G, int gsn) {
    __shared__ int bins[64 * MAXG];
    __shared__ int ls[256];
    const int rt = blockIdx.x;
    const int nb = 64 * G;
    const int e0 = sptr[(size_t)rt * NCH];
    const int e1 = sptr[(size_t)(rt + 1) * NCH];

    for (int i = threadIdx.x; i < nb; i += 256) bins[i] = 0;
    __syncthreads();
    for (int e = e0 + threadIdx.x; e < e1; e += 256) {
        unsigned pv = pay[e];
        int row = (int)(pv & 63u);
        int g = (int)((pv >> 6) / (unsigned)gsn);
        atomicAdd(&bins[row * G + g], 1);
    }
    __syncthreads();

    // block exclusive scan over nb bins (nb <= 2048)
    int loc[8];
    int s = 0;
#pragma unroll 8
    for (int i = 0; i < 8; ++i) {
        int idx = threadIdx.x * 8 + i;
        int v = (idx < nb) ? bins[idx] : 0;
        loc[i] = s; s += v;
    }
    ls[threadIdx.x] = s;
    __syncthreads();
    for (int o = 1; o < 256; o <<= 1) {
        int add = ((int)threadIdx.x >= o) ? ls[threadIdx.x - o] : 0;
        __syncthreads();
        ls[threadIdx.x] += add;
        __syncthreads();
    }
    int excl = ls[threadIdx.x] - s + e0;
    __syncthreads();
#pragma unroll 8
    for (int i = 0; i < 8; ++i) {
        int idx = threadIdx.x * 8 + i;
        if (idx < nb) bins[idx] = excl + loc[i];
    }
    __syncthreads();

    // publish rp3 boundaries
    for (int idx = threadIdx.x; idx < nb; idx += 256) {
        int row = idx / G;
        int g = idx - row * G;
        int r = (rt << 6) + row;
        if (r < n) rp3[(size_t)r * G + g] = bins[idx];
    }
    __syncthreads();

    // scatter: rank via LDS atomic on the scanned bases
    for (int e = e0 + threadIdx.x; e < e1; e += 256) {
        unsigned pv = pay[e];
        int row = (int)(pv & 63u);
        int g = (int)((pv >> 6) / (unsigned)gsn);
        int p = atomicAdd(&bins[row * G + g], 1);
        pay2[p] = pv >> 6;
    }
}

// ---------------- conv phase A: gathered GEMM -> y linear at local t ----------------
// y row = 64 u32; u32 index (l15*4+cp) holds true cols (l15+32cp, l15+32cp+16).
__global__ __launch_bounds__(512) void gemm_y_grp(
    const unsigned short* __restrict__ xin,   // [n,128] bf16 true layout
    const unsigned short* __restrict__ Wb,    // group base [ks][32][64][8]
    const int* __restrict__ idx_in,           // group base [ks,n]
    unsigned* __restrict__ yu,                // [gs*n, 64]
    int n) {
    __shared__ unsigned short wlds[16384];
    const int k = blockIdx.y;
    const int m0 = blockIdx.x * 256;
    {
        const bf16x8* src = (const bf16x8*)(Wb + (size_t)k * 16384);
        bf16x8* dst = (bf16x8*)wlds;
        for (int i = threadIdx.x; i < 2048; i += 512) dst[i] = src[i];
    }
    __syncthreads();

    const int wave = threadIdx.x >> 6;
    const int lane = threadIdx.x & 63;
    const int kg = lane >> 4;
    const int l15 = lane & 15;

    const int* iin = idx_in + (size_t)k * n;
    const int mbase = m0 + wave * 32;

    int arow0, arow1;
    { int m = mbase + l15;      arow0 = (m < n) ? iin[m] : 0; }
    { int m = mbase + 16 + l15; arow1 = (m < n) ? iin[m] : 0; }

    f32x4 acc[2][8];
#pragma unroll
    for (int s = 0; s < 2; ++s)
#pragma unroll
        for (int c = 0; c < 8; ++c) acc[s][c] = (f32x4){0.f, 0.f, 0.f, 0.f};

#pragma unroll
    for (int kk = 0; kk < 4; ++kk) {
        bf16x8 a0 = *(const bf16x8*)(xin + (size_t)arow0 * 128 + kk * 32 + kg * 8);
        bf16x8 a1 = *(const bf16x8*)(xin + (size_t)arow1 * 128 + kk * 32 + kg * 8);
#pragma unroll
        for (int c = 0; c < 8; ++c) {
            bf16x8 b = *(const bf16x8*)(wlds + ((kk * 8 + c) * 64 + lane) * 8);
            acc[0][c] = __builtin_amdgcn_mfma_f32_16x16x32_bf16(a0, b, acc[0][c], 0, 0, 0);
            acc[1][c] = __builtin_amdgcn_mfma_f32_16x16x32_bf16(a1, b, acc[1][c], 0, 0, 0);
        }
    }

#pragma unroll
    for (int s = 0; s < 2; ++s) {
#pragma unroll
        for (int j = 0; j < 4; ++j) {
            int m = mbase + s * 16 + kg * 4 + j;
            if (m < n) {
                u32x4 v;
#pragma unroll
                for (int cp = 0; cp < 4; ++cp) {
                    unsigned pk;
                    asm("v_cvt_pk_bf16_f32 %0, %1, %2"
                        : "=v"(pk)
                        : "v"(acc[s][2 * cp][j]), "v"(acc[s][2 * cp + 1][j]));
                    v[cp] = pk;
                }
                *(u32x4*)(yu + ((size_t)k * n + m) * 64 + l15 * 4) = v;   // L3-resident
            }
        }
    }
}

// ---------------- conv phase B: per-(row,group) register segment reduce ----------------
// lane l owns u32 column l: true cols tc0 = (l>>2)+32*(l&3) and tc0+16.
__global__ __launch_bounds__(256) void reduce_y_g(
    const unsigned* __restrict__ yu, const unsigned* __restrict__ pay2,
    const int* __restrict__ rp3, float* __restrict__ hbuf, float* __restrict__ stats,
    int n, int G, int g, int gsn, int nk, int accum, int do_stats) {
    const int w = threadIdx.x >> 6, l = threadIdx.x & 63;
    const int tc0 = (l >> 2) + 32 * (l & 3);
    const unsigned gbase = (unsigned)g * (unsigned)gsn;
    float s0 = 0.f, q0 = 0.f, s1 = 0.f, q1 = 0.f;

    for (int r = blockIdx.x * 4 + w; r < n; r += gridDim.x * 4) {
        size_t idx = (size_t)r * G + g;
        int e = rp3[idx];
        const int e1 = (idx + 1 == (size_t)n * G) ? nk : rp3[idx + 1];
        float a0 = 0.f, a1 = 0.f;
        for (; e < e1; ++e) {
            unsigned t = pay2[e];
            unsigned v = yu[(size_t)(t - gbase) * 64 + l];
            a0 += __builtin_bit_cast(float, v << 16);
            a1 += __builtin_bit_cast(float, v & 0xffff0000u);
        }
        float* dst = hbuf + (size_t)r * 128 + tc0;
        if (accum) { a0 += dst[0]; a1 += dst[16]; }
        dst[0] = a0; dst[16] = a1;
        if (do_stats) { s0 += a0; q0 += a0 * a0; s1 += a1; q1 += a1 * a1; }
    }

    if (do_stats) {
        __shared__ float ls[4][64][4];
        ls[w][l][0] = s0; ls[w][l][1] = q0; ls[w][l][2] = s1; ls[w][l][3] = q1;
        __syncthreads();
        if (w == 0) {
            float t0 = 0, t1 = 0, t2 = 0, t3 = 0;
#pragma unroll
            for (int ww = 0; ww < 4; ++ww) {
                t0 += ls[ww][l][0]; t1 += ls[ww][l][1];
                t2 += ls[ww][l][2]; t3 += ls[ww][l][3];
            }
            atomicAdd(&stats[tc0], t0);       atomicAdd(&stats[128 + tc0], t1);
            atomicAdd(&stats[tc0 + 16], t2);  atomicAdd(&stats[128 + tc0 + 16], t3);
        }
    }
}

// ---------------- last-ditch fallback: atomic conv (R1, proven) ----------------
__global__ __launch_bounds__(512) void conv_atomic(
    const unsigned short* __restrict__ xin, const unsigned short* __restrict__ Wb,
    const int* __restrict__ idx_in, const int* __restrict__ idx_out,
    float* __restrict__ out, int n) {
    __shared__ unsigned short wlds[16384];
    const int k = blockIdx.y;
    const int m0 = blockIdx.x * 256;
    {
        const bf16x8* src = (const bf16x8*)(Wb + (size_t)k * 16384);
        bf16x8* dst = (bf16x8*)wlds;
        for (int i = threadIdx.x; i < 2048; i += 512) dst[i] = src[i];
    }
    __syncthreads();
    const int wave = threadIdx.x >> 6;
    const int lane = threadIdx.x & 63;
    const int kg = lane >> 4;
    const int l15 = lane & 15;
    const int* iin  = idx_in  + (size_t)k * n;
    const int* iout = idx_out + (size_t)k * n;
    const int mbase = m0 + wave * 32;
    int arow0, arow1;
    { int m = mbase + l15;      arow0 = (m < n) ? iin[m] : 0; }
    { int m = mbase + 16 + l15; arow1 = (m < n) ? iin[m] : 0; }
    f32x4 acc[2][8];
#pragma unroll
    for (int s = 0; s < 2; ++s)
#pragma unroll
        for (int c = 0; c < 8; ++c) acc[s][c] = (f32x4){0.f, 0.f, 0.f, 0.f};
#pragma unroll
    for (int kk = 0; kk < 4; ++kk) {
        bf16x8 a0 = *(const bf16x8*)(xin + (size_t)arow0 * 128 + kk * 32 + kg * 8);
        bf16x8 a1 = *(const bf16x8*)(xin + (size_t)arow1 * 128 + kk * 32 + kg * 8);
#pragma unroll
        for (int c = 0; c < 8; ++c) {
            bf16x8 b = *(const bf16x8*)(wlds + ((kk * 8 + c) * 64 + lane) * 8);
            acc[0][c] = __builtin_amdgcn_mfma_f32_16x16x32_bf16(a0, b, acc[0][c], 0, 0, 0);
            acc[1][c] = __builtin_amdgcn_mfma_f32_16x16x32_bf16(a1, b, acc[1][c], 0, 0, 0);
        }
    }
#pragma unroll
    for (int s = 0; s < 2; ++s)
#pragma unroll
        for (int j = 0; j < 4; ++j) {
            int m = mbase + s * 16 + kg * 4 + j;
            if (m < n) {
                long orow = iout[m];
                float* dst = out + orow * 128 + l15;
#pragma unroll
                for (int c = 0; c < 8; ++c) atomicAdd(dst + c * 16, acc[s][c][j]);
            }
        }
}

// ---------------- BN epilogues (true layout f32 h) ----------------

__global__ void bn_stats(const float* __restrict__ h, float* __restrict__ stats, int n) {
    const int c = threadIdx.x & 127;
    const int half = threadIdx.x >> 7;
    const int r0 = blockIdx.x * 256;
    const int rend = min(r0 + 256, n);
    float s = 0.f, s2 = 0.f;
    for (int r = r0 + half; r < rend; r += 2) {
        float v = h[(size_t)r * 128 + c];
        s += v; s2 += v * v;
    }
    __shared__ float ls[256], ls2[256];
    ls[threadIdx.x] = s; ls2[threadIdx.x] = s2;
    __syncthreads();
    if (half == 0) {
        atomicAdd(&stats[c], ls[c] + ls[128 + c]);
        atomicAdd(&stats[128 + c], ls2[c] + ls2[128 + c]);
    }
}

__global__ void bn_finalize(float* stats, const float* __restrict__ g,
                            const float* __restrict__ b, float inv_n) {
    int c = threadIdx.x;
    float mu = stats[c] * inv_n;
    float var = fmaxf(stats[128 + c] * inv_n - mu * mu, 0.f);
    float sc = g[c] * rsqrtf(var + 1e-5f);
    stats[256 + c] = sc;
    stats[384 + c] = b[c] - mu * sc;
}

__global__ void bn_relu_bf16(const float* __restrict__ h, const float* __restrict__ stats,
                             unsigned short* __restrict__ hb, long total) {
    long i = ((long)blockIdx.x * 256 + threadIdx.x) * 4;
    if (i >= total) return;
    int c = (int)(i & 127);
    f32x4 v = *(const f32x4*)(h + i);
    u16x4 r;
#pragma unroll
    for (int t = 0; t < 4; ++t) {
        float y = fmaxf(v[t] * stats[256 + c + t] + stats[384 + c + t], 0.f);
        r[t] = f2b(y);
    }
    *(u16x4*)(hb + i) = r;
}

__global__ void bn_res_relu(float* __restrict__ out, const float* __restrict__ stats,
                            const float* __restrict__ x, long total) {
    long i = ((long)blockIdx.x * 256 + threadIdx.x) * 4;
    if (i >= total) return;
    int c = (int)(i & 127);
    f32x4 h = *(const f32x4*)(out + i);
    f32x4 xv = *(const f32x4*)(x + i);
    f32x4 r;
#pragma unroll
    for (int t = 0; t < 4; ++t)
        r[t] = fmaxf(h[t] * stats[256 + c + t] + stats[384 + c + t] + xv[t], 0.f);
    *(f32x4*)(out + i) = r;
}

extern "C" void kernel_launch(void* const* d_in, const int* in_sizes, int n_in,
                              void* d_out, int out_size, void* d_ws, size_t ws_size,
                              hipStream_t stream) {
    const float* x  = (const float*)d_in[0];
    const float* W1 = (const float*)d_in[1];
    const float* g1 = (const float*)d_in[2];
    const float* b1 = (const float*)d_in[3];
    const float* W2 = (const float*)d_in[4];
    const float* g2 = (const float*)d_in[5];
    const float* b2 = (const float*)d_in[6];
    const int* idx_in  = (const int*)d_in[7];
    const int* idx_out = (const int*)d_in[8];

    const int n = in_sizes[0] / 128;
    const int K = in_sizes[1] / 16384;
    const long total = (long)n * 128;
    const int nk = K * n;
    float* acc = (float*)d_out;

    char* ws = (char*)d_ws;
    auto align256 = [](size_t v) { return (v + 255) & ~255ULL; };

    // fixed allocations
    size_t off = 0;
    const size_t o_slabA = off; off = align256(off + (size_t)total * 2);
    const size_t o_Wb1   = off; off = align256(off + (size_t)K * 16384 * 2);
    const size_t o_Wb2   = off; off = align256(off + (size_t)K * 16384 * 2);
    const size_t o_stats = off; off = align256(off + 1024 * 4);
    const size_t fixed_end = off;

    unsigned short* slabA = (unsigned short*)(ws + o_slabA);
    unsigned short* Wb1   = (unsigned short*)(ws + o_Wb1);
    unsigned short* Wb2   = (unsigned short*)(ws + o_Wb2);
    float* stats          = (float*)(ws + o_stats);

    const dim3 b256(256);
    const int gCvt = (int)((total / 4 + 255) / 256);
    const int kelems = K * 16384;

    hipLaunchKernelGGL(zero_f32, dim3(1), b256, 0, stream, stats, (long)1024);
    hipLaunchKernelGGL(cvt_bf16, dim3(gCvt), b256, 0, stream, x, slabA, total);
    hipLaunchKernelGGL(prep_w, dim3((2 * kelems + 255) / 256), b256, 0, stream,
                       W1, W2, Wb1, Wb2, kelems);

    // sort geometry (grouping-independent)
    const int NT  = (n + 63) / 64;
    const int NCH = (nk + CH2 - 1) / CH2;
    const long nbinsS = (long)NT * NCH;
    const long nbS = (nbinsS + 4095) / 4096;

    // pick largest gs (cap 6: y = gs*n*256B stays L3-resident alongside h + x)
    const int gs_cap = (K < 6) ? K : 6;
    int gs = 0, G = 0;
    size_t o_pay = 0, o_pay2 = 0, o_rp3 = 0, o_cntS = 0, o_sptS = 0, o_bsmS = 0, o_y = 0;
    for (int cand = gs_cap; cand >= 1; --cand) {
        int gc = (K + cand - 1) / cand;
        if (gc > MAXG) break;
        off = fixed_end;
        size_t t_pay  = off; off = align256(off + (size_t)nk * 4);
        size_t t_pay2 = off; off = align256(off + (size_t)nk * 4);
        size_t t_rp3  = off; off = align256(off + ((size_t)n * gc + 1) * 4);
        size_t t_cnt  = off; off = align256(off + (size_t)nbinsS * 4);
        size_t t_spt  = off; off = align256(off + ((size_t)nbinsS + 1) * 4);
        size_t t_bsm  = off; off = align256(off + ((size_t)nbS + 2) * 4);
        size_t t_y    = off; off += (size_t)cand * (size_t)n * 256;
        if (off <= ws_size) {
            gs = cand; G = gc;
            o_pay = t_pay; o_pay2 = t_pay2; o_rp3 = t_rp3;
            o_cntS = t_cnt; o_sptS = t_spt; o_bsmS = t_bsm; o_y = t_y;
            break;
        }
    }

    if (gs > 0 && NT <= MAXNT) {
        unsigned* pay  = (unsigned*)(ws + o_pay);
        unsigned* pay2 = (unsigned*)(ws + o_pay2);
        int* rp3       = (int*)(ws + o_rp3);
        int* cntS      = (int*)(ws + o_cntS);
        int* sptS      = (int*)(ws + o_sptS);
        int* bsmS      = (int*)(ws + o_bsmS);
        unsigned* yu   = (unsigned*)(ws + o_y);
        const int gsn = gs * n;

        // CSR build: two LDS-atomic sorts, no global return-atomics
        hipLaunchKernelGGL(pass_hist_t, dim3(NCH), b256, 0, stream, idx_out, cntS, nk, NT, NCH);
        hipLaunchKernelGGL(scan_part, dim3((int)nbS), b256, 0, stream, cntS, bsmS, (int)nbinsS);
        hipLaunchKernelGGL(scan_bsum, dim3(1), dim3(64), 0, stream, bsmS, (int)nbS, sptS, (int)nbinsS);
        hipLaunchKernelGGL(scan_final, dim3((int)nbS), b256, 0, stream, cntS, bsmS, sptS, (int)nbinsS);
        hipLaunchKernelGGL(pass_scatter_t, dim3(NCH), b256, 0, stream, idx_out, sptS, pay, nk, NT, NCH);
        hipLaunchKernelGGL(sort2_tile_g, dim3(NT), b256, 0, stream, pay, sptS, pay2, rp3, n, NCH, G, gsn);

        for (int conv = 0; conv < 2; ++conv) {
            const unsigned short* Wb = conv ? Wb2 : Wb1;
            float* st = stats + conv * 512;
            for (int g = 0; g < G; ++g) {
                int ks = min(gs, K - g * gs);
                hipLaunchKernelGGL(gemm_y_grp, dim3((n + 255) / 256, ks), dim3(512), 0, stream,
                                   slabA, Wb + (size_t)g * gs * 16384,
                                   idx_in + (size_t)g * gsn, yu, n);
                hipLaunchKernelGGL(reduce_y_g, dim3(2048), b256, 0, stream,
                                   yu, pay2, rp3, acc, st,
                                   n, G, g, gsn, nk, (g > 0) ? 1 : 0, (g == G - 1) ? 1 : 0);
            }
            hipLaunchKernelGGL(bn_finalize, dim3(1), dim3(128), 0, stream, st,
                               conv ? g2 : g1, conv ? b2 : b1, 1.0f / n);
            if (conv == 0)
                hipLaunchKernelGGL(bn_relu_bf16, dim3(gCvt), b256, 0, stream, acc, st, slabA, total);
            else
                hipLaunchKernelGGL(bn_res_relu, dim3(gCvt), b256, 0, stream, acc, st, x, total);
        }
    } else {
        for (int conv = 0; conv < 2; ++conv) {
            const unsigned short* Wb = conv ? Wb2 : Wb1;
            float* st = stats + conv * 512;
            hipLaunchKernelGGL(zero_f32, dim3(gCvt), b256, 0, stream, acc, total);
            hipLaunchKernelGGL(conv_atomic, dim3((n + 255) / 256, K), dim3(512), 0, stream,
                               slabA, Wb, idx_in, idx_out, acc, n);
            hipLaunchKernelGGL(bn_stats, dim3((n + 255) / 256), b256, 0, stream, acc, st, n);
            hipLaunchKernelGGL(bn_finalize, dim3(1), dim3(128), 0, stream, st,
                               conv ? g2 : g1, conv ? b2 : b1, 1.0f / n);
            if (conv == 0)
                hipLaunchKernelGGL(bn_relu_bf16, dim3(gCvt), b256, 0, stream, acc, st, slabA, total);
            else
                hipLaunchKernelGGL(bn_res_relu, dim3(gCvt), b256, 0, stream, acc, st, x, total);
        }
    }
}

// Round 9
// 1272.237 us; speedup vs baseline: 1.1114x; 1.1114x over previous
//
#include <hip/hip_runtime.h>

typedef __attribute__((ext_vector_type(8))) short bf16x8;
typedef __attribute__((ext_vector_type(4))) float f32x4;
typedef __attribute__((ext_vector_type(4))) unsigned short u16x4;
typedef __attribute__((ext_vector_type(4))) unsigned u32x4;

__device__ __forceinline__ unsigned short f2b(float f) {
    unsigned u = __builtin_bit_cast(unsigned, f);
    u += 0x7fffu + ((u >> 16) & 1u);   // round-to-nearest-even
    return (unsigned short)(u >> 16);
}

__global__ void zero_f32(float* __restrict__ p, long total) {
    long i = ((long)blockIdx.x * blockDim.x + threadIdx.x) * 4;
    if (i + 3 < total) {
        *(f32x4*)(p + i) = (f32x4){0.f, 0.f, 0.f, 0.f};
    } else {
        for (long t = i; t < total; ++t) p[t] = 0.f;
    }
}

__global__ void cvt_bf16(const float* __restrict__ x, unsigned short* __restrict__ o, long total) {
    long i = ((long)blockIdx.x * blockDim.x + threadIdx.x) * 4;
    if (i >= total) return;
    f32x4 v = *(const f32x4*)(x + i);
    u16x4 r;
#pragma unroll
    for (int t = 0; t < 4; ++t) r[t] = f2b(v[t]);
    *(u16x4*)(o + i) = r;
}

// Wb[k][frag f=kk*8+c][lane][j] = W[k][cin=kk*32+(lane>>4)*8+j][cout=c*16+(lane&15)]
__global__ void prep_w(const float* __restrict__ W1, const float* __restrict__ W2,
                       unsigned short* __restrict__ Wb1, unsigned short* __restrict__ Wb2,
                       int kelems) {
    int tid = blockIdx.x * 256 + threadIdx.x;
    if (tid >= 2 * kelems) return;
    int which = (tid >= kelems) ? 1 : 0;
    int rem = which ? (tid - kelems) : tid;
    int k = rem >> 14;
    int r2 = rem & 16383;
    int f = r2 >> 9;
    int lane = (r2 >> 3) & 63;
    int j = r2 & 7;
    int kk = f >> 3, c = f & 7;
    int cin = kk * 32 + (lane >> 4) * 8 + j;
    int cout = c * 16 + (lane & 15);
    const float* W = which ? W2 : W1;
    unsigned short* Wb = which ? Wb2 : Wb1;
    Wb[rem] = f2b(W[(size_t)k * 16384 + cin * 128 + cout]);
}

// ---------------- CSR build: bins g-major (bin = g*n + r), cnt padded 1 bin / 64B line ----------------

// single atomic pass: rank[t] = running count of bin (LINEAR write of rank).
__global__ void hist_rank(const int* __restrict__ io, int* __restrict__ cnt,
                          int* __restrict__ rank, int nk, int gsn, int n, int G) {
    int t = blockIdx.x * 256 + threadIdx.x;
    if (t >= nk) return;
    int r = io[t];
    int g = (G == 1) ? 0 : (t / gsn);
    rank[t] = atomicAdd(&cnt[((size_t)g * n + r) << 4], 1);
}

__global__ void scan_part(const int* __restrict__ cnt, int* __restrict__ bsum, int nbins) {
    __shared__ int ls[256];
    int base = blockIdx.x * 4096 + threadIdx.x * 16;
    int s = 0;
#pragma unroll
    for (int i = 0; i < 16; ++i) { int idx = base + i; if (idx < nbins) s += cnt[(size_t)idx << 4]; }
    ls[threadIdx.x] = s; __syncthreads();
    for (int o = 128; o > 0; o >>= 1) {
        if ((int)threadIdx.x < o) ls[threadIdx.x] += ls[threadIdx.x + o];
        __syncthreads();
    }
    if (threadIdx.x == 0) bsum[blockIdx.x] = ls[0];
}

__global__ void scan_bsum(int* __restrict__ bsum, int nb, int* __restrict__ sptr, int nbins) {
    if (threadIdx.x == 0 && blockIdx.x == 0) {
        int run = 0;
        for (int i = 0; i < nb; ++i) { int t = bsum[i]; bsum[i] = run; run += t; }
        sptr[nbins] = run;
    }
}

__global__ void scan_final(const int* __restrict__ cnt, const int* __restrict__ bsum,
                           int* __restrict__ sptr, int nbins) {
    __shared__ int ls[256];
    const int tid = threadIdx.x;
    int base = blockIdx.x * 4096 + tid * 16;
    int loc[16];
    int s = 0;
#pragma unroll
    for (int i = 0; i < 16; ++i) {
        int idx = base + i;
        int v = (idx < nbins) ? cnt[(size_t)idx << 4] : 0;
        loc[i] = s; s += v;
    }
    ls[tid] = s; __syncthreads();
    for (int o = 1; o < 256; o <<= 1) {
        int add = (tid >= o) ? ls[tid - o] : 0;
        __syncthreads();
        ls[tid] += add;
        __syncthreads();
    }
    int excl = ls[tid] - s + bsum[blockIdx.x];
#pragma unroll
    for (int i = 0; i < 16; ++i) {
        int idx = base + i;
        if (idx < nbins) sptr[idx] = excl + loc[i];
    }
}

// ---------------- Phase A: gathered GEMM -> y at CSR slot (slot computed inline) ----------------
// y row = 64 u32; u32 index (l15*4+cp) holds true cols (l15+32cp, l15+32cp+16).
__global__ __launch_bounds__(512) void gemm_y_slot(
    const unsigned short* __restrict__ xin,   // [n,128] bf16 true layout
    const unsigned short* __restrict__ Wb,    // group base [ks][32][64][8]
    const int* __restrict__ iing,             // idx_in  + g*gsn
    const int* __restrict__ iog,              // idx_out + g*gsn
    const int* __restrict__ rankg,            // rank    + g*gsn
    const int* __restrict__ rpg,              // row_ptr + g*n   (values are global; subtract gbase)
    unsigned* __restrict__ yu,                // [gs*n, 64]
    int n, int gbase)                         // gbase = g*gs*n
{
    __shared__ unsigned short wlds[16384];
    __shared__ int sslot[256];
    const int k = blockIdx.y;
    const int m0 = blockIdx.x * 256;

    {
        const bf16x8* src = (const bf16x8*)(Wb + (size_t)k * 16384);
        bf16x8* dst = (bf16x8*)wlds;
        for (int i = threadIdx.x; i < 2048; i += 512) dst[i] = src[i];
        if (threadIdx.x < 256) {
            int m = m0 + threadIdx.x;
            int tl = k * n + m;
            sslot[threadIdx.x] = (m < n) ? (rpg[iog[tl]] + rankg[tl] - gbase) : 0;
        }
    }
    __syncthreads();

    const int wave = threadIdx.x >> 6;
    const int lane = threadIdx.x & 63;
    const int kg = lane >> 4;
    const int l15 = lane & 15;

    const int* iin = iing + (size_t)k * n;
    const int mbase = m0 + wave * 32;

    int arow0, arow1;
    { int m = mbase + l15;      arow0 = (m < n) ? iin[m] : 0; }
    { int m = mbase + 16 + l15; arow1 = (m < n) ? iin[m] : 0; }

    f32x4 acc[2][8];
#pragma unroll
    for (int s = 0; s < 2; ++s)
#pragma unroll
        for (int c = 0; c < 8; ++c) acc[s][c] = (f32x4){0.f, 0.f, 0.f, 0.f};

#pragma unroll
    for (int kk = 0; kk < 4; ++kk) {
        bf16x8 a0 = *(const bf16x8*)(xin + (size_t)arow0 * 128 + kk * 32 + kg * 8);
        bf16x8 a1 = *(const bf16x8*)(xin + (size_t)arow1 * 128 + kk * 32 + kg * 8);
#pragma unroll
        for (int c = 0; c < 8; ++c) {
            bf16x8 b = *(const bf16x8*)(wlds + ((kk * 8 + c) * 64 + lane) * 8);
            acc[0][c] = __builtin_amdgcn_mfma_f32_16x16x32_bf16(a0, b, acc[0][c], 0, 0, 0);
            acc[1][c] = __builtin_amdgcn_mfma_f32_16x16x32_bf16(a1, b, acc[1][c], 0, 0, 0);
        }
    }

    // value acc[s][c][j]: gathered row m = mbase+s*16+kg*4+j, true col l15+16c
#pragma unroll
    for (int s = 0; s < 2; ++s) {
#pragma unroll
        for (int j = 0; j < 4; ++j) {
            int m = mbase + s * 16 + kg * 4 + j;
            if (m < n) {
                u32x4 v;
#pragma unroll
                for (int cp = 0; cp < 4; ++cp) {
                    unsigned pk;
                    asm("v_cvt_pk_bf16_f32 %0, %1, %2"
                        : "=v"(pk)
                        : "v"(acc[s][2 * cp][j]), "v"(acc[s][2 * cp + 1][j]));
                    v[cp] = pk;
                }
                int p = sslot[m - m0];
                *(u32x4*)(yu + (size_t)p * 64 + l15 * 4) = v;
            }
        }
    }
}

// ---------------- Phase B: contiguous segment reduce (+ fused BN stats on last group) -------------
// lane l owns u32 column l: true cols tc0 = (l>>2)+32*(l&3) and tc0+16.
__global__ __launch_bounds__(256) void reduce_y_grp(
    const unsigned* __restrict__ yu, const int* __restrict__ rp,
    float* __restrict__ hbuf, float* __restrict__ stats,
    int n, int base, int accum, int do_stats) {
    const int w = threadIdx.x >> 6, l = threadIdx.x & 63;
    const int tc0 = (l >> 2) + 32 * (l & 3);
    float s0 = 0.f, q0 = 0.f, s1 = 0.f, q1 = 0.f;
    for (int r = blockIdx.x * 4 + w; r < n; r += gridDim.x * 4) {
        int e = rp[r] - base;
        const int e1 = rp[r + 1] - base;
        float a0 = 0.f, a1 = 0.f;
        for (; e < e1; ++e) {
            unsigned v = yu[(size_t)e * 64 + l];
            a0 += __builtin_bit_cast(float, v << 16);
            a1 += __builtin_bit_cast(float, v & 0xffff0000u);
        }
        float* dst = hbuf + (size_t)r * 128 + tc0;
        if (accum) { a0 += dst[0]; a1 += dst[16]; }
        dst[0] = a0; dst[16] = a1;
        if (do_stats) { s0 += a0; q0 += a0 * a0; s1 += a1; q1 += a1 * a1; }
    }
    if (do_stats) {
        __shared__ float ls[4][64][4];
        ls[w][l][0] = s0; ls[w][l][1] = q0; ls[w][l][2] = s1; ls[w][l][3] = q1;
        __syncthreads();
        if (w == 0) {
            float t0 = 0, t1 = 0, t2 = 0, t3 = 0;
#pragma unroll
            for (int ww = 0; ww < 4; ++ww) {
                t0 += ls[ww][l][0]; t1 += ls[ww][l][1];
                t2 += ls[ww][l][2]; t3 += ls[ww][l][3];
            }
            atomicAdd(&stats[tc0], t0);       atomicAdd(&stats[128 + tc0], t1);
            atomicAdd(&stats[tc0 + 16], t2);  atomicAdd(&stats[128 + tc0 + 16], t3);
        }
    }
}

// ---------------- fallback: atomic conv (R1, proven) ----------------
__global__ __launch_bounds__(512) void conv_atomic(
    const unsigned short* __restrict__ xin, const unsigned short* __restrict__ Wb,
    const int* __restrict__ idx_in, const int* __restrict__ idx_out,
    float* __restrict__ out, int n) {
    __shared__ unsigned short wlds[16384];
    const int k = blockIdx.y;
    const int m0 = blockIdx.x * 256;
    {
        const bf16x8* src = (const bf16x8*)(Wb + (size_t)k * 16384);
        bf16x8* dst = (bf16x8*)wlds;
        for (int i = threadIdx.x; i < 2048; i += 512) dst[i] = src[i];
    }
    __syncthreads();
    const int wave = threadIdx.x >> 6;
    const int lane = threadIdx.x & 63;
    const int kg = lane >> 4;
    const int l15 = lane & 15;
    const int* iin  = idx_in  + (size_t)k * n;
    const int* iout = idx_out + (size_t)k * n;
    const int mbase = m0 + wave * 32;
    int arow0, arow1;
    { int m = mbase + l15;      arow0 = (m < n) ? iin[m] : 0; }
    { int m = mbase + 16 + l15; arow1 = (m < n) ? iin[m] : 0; }
    f32x4 acc[2][8];
#pragma unroll
    for (int s = 0; s < 2; ++s)
#pragma unroll
        for (int c = 0; c < 8; ++c) acc[s][c] = (f32x4){0.f, 0.f, 0.f, 0.f};
#pragma unroll
    for (int kk = 0; kk < 4; ++kk) {
        bf16x8 a0 = *(const bf16x8*)(xin + (size_t)arow0 * 128 + kk * 32 + kg * 8);
        bf16x8 a1 = *(const bf16x8*)(xin + (size_t)arow1 * 128 + kk * 32 + kg * 8);
#pragma unroll
        for (int c = 0; c < 8; ++c) {
            bf16x8 b = *(const bf16x8*)(wlds + ((kk * 8 + c) * 64 + lane) * 8);
            acc[0][c] = __builtin_amdgcn_mfma_f32_16x16x32_bf16(a0, b, acc[0][c], 0, 0, 0);
            acc[1][c] = __builtin_amdgcn_mfma_f32_16x16x32_bf16(a1, b, acc[1][c], 0, 0, 0);
        }
    }
#pragma unroll
    for (int s = 0; s < 2; ++s)
#pragma unroll
        for (int j = 0; j < 4; ++j) {
            int m = mbase + s * 16 + kg * 4 + j;
            if (m < n) {
                long orow = iout[m];
                float* dst = out + orow * 128 + l15;
#pragma unroll
                for (int c = 0; c < 8; ++c) atomicAdd(dst + c * 16, acc[s][c][j]);
            }
        }
}

// ---------------- BN epilogues (true layout f32 h) ----------------

__global__ void bn_stats(const float* __restrict__ h, float* __restrict__ stats, int n) {
    const int c = threadIdx.x & 127;
    const int half = threadIdx.x >> 7;
    const int r0 = blockIdx.x * 256;
    const int rend = min(r0 + 256, n);
    float s = 0.f, s2 = 0.f;
    for (int r = r0 + half; r < rend; r += 2) {
        float v = h[(size_t)r * 128 + c];
        s += v; s2 += v * v;
    }
    __shared__ float ls[256], ls2[256];
    ls[threadIdx.x] = s; ls2[threadIdx.x] = s2;
    __syncthreads();
    if (half == 0) {
        atomicAdd(&stats[c], ls[c] + ls[128 + c]);
        atomicAdd(&stats[128 + c], ls2[c] + ls2[128 + c]);
    }
}

__global__ void bn_finalize(float* stats, const float* __restrict__ g,
                            const float* __restrict__ b, float inv_n) {
    int c = threadIdx.x;
    float mu = stats[c] * inv_n;
    float var = fmaxf(stats[128 + c] * inv_n - mu * mu, 0.f);
    float sc = g[c] * rsqrtf(var + 1e-5f);
    stats[256 + c] = sc;
    stats[384 + c] = b[c] - mu * sc;
}

__global__ void bn_relu_bf16(const float* __restrict__ h, const float* __restrict__ stats,
                             unsigned short* __restrict__ hb, long total) {
    long i = ((long)blockIdx.x * 256 + threadIdx.x) * 4;
    if (i >= total) return;
    int c = (int)(i & 127);
    f32x4 v = *(const f32x4*)(h + i);
    u16x4 r;
#pragma unroll
    for (int t = 0; t < 4; ++t) {
        float y = fmaxf(v[t] * stats[256 + c + t] + stats[384 + c + t], 0.f);
        r[t] = f2b(y);
    }
    *(u16x4*)(hb + i) = r;
}

__global__ void bn_res_relu(float* __restrict__ out, const float* __restrict__ stats,
                            const float* __restrict__ x, long total) {
    long i = ((long)blockIdx.x * 256 + threadIdx.x) * 4;
    if (i >= total) return;
    int c = (int)(i & 127);
    f32x4 h = *(const f32x4*)(out + i);
    f32x4 xv = *(const f32x4*)(x + i);
    f32x4 r;
#pragma unroll
    for (int t = 0; t < 4; ++t)
        r[t] = fmaxf(h[t] * stats[256 + c + t] + stats[384 + c + t] + xv[t], 0.f);
    *(f32x4*)(out + i) = r;
}

extern "C" void kernel_launch(void* const* d_in, const int* in_sizes, int n_in,
                              void* d_out, int out_size, void* d_ws, size_t ws_size,
                              hipStream_t stream) {
    const float* x  = (const float*)d_in[0];
    const float* W1 = (const float*)d_in[1];
    const float* g1 = (const float*)d_in[2];
    const float* b1 = (const float*)d_in[3];
    const float* W2 = (const float*)d_in[4];
    const float* g2 = (const float*)d_in[5];
    const float* b2 = (const float*)d_in[6];
    const int* idx_in  = (const int*)d_in[7];
    const int* idx_out = (const int*)d_in[8];

    const int n = in_sizes[0] / 128;
    const int K = in_sizes[1] / 16384;
    const long total = (long)n * 128;
    const int nk = K * n;
    float* acc = (float*)d_out;

    char* ws = (char*)d_ws;
    auto align256 = [](size_t v) { return (v + 255) & ~255ULL; };

    // fixed allocations
    size_t off = 0;
    const size_t o_slabA = off; off = align256(off + (size_t)total * 2);
    const size_t o_Wb1   = off; off = align256(off + (size_t)K * 16384 * 2);
    const size_t o_Wb2   = off; off = align256(off + (size_t)K * 16384 * 2);
    const size_t o_stats = off; off = align256(off + 1024 * 4);
    const size_t o_rank  = off; off = align256(off + (size_t)nk * 4);
    const size_t fixed_end = off;

    unsigned short* slabA = (unsigned short*)(ws + o_slabA);
    unsigned short* Wb1   = (unsigned short*)(ws + o_Wb1);
    unsigned short* Wb2   = (unsigned short*)(ws + o_Wb2);
    float* stats          = (float*)(ws + o_stats);
    int* rank             = (int*)(ws + o_rank);

    const dim3 b256(256);
    const int gCvt = (int)((total / 4 + 255) / 256);
    const int kelems = K * 16384;

    hipLaunchKernelGGL(zero_f32, dim3(1), b256, 0, stream, stats, (long)1024);
    hipLaunchKernelGGL(cvt_bf16, dim3(gCvt), b256, 0, stream, x, slabA, total);
    hipLaunchKernelGGL(prep_w, dim3((2 * kelems + 255) / 256), b256, 0, stream,
                       W1, W2, Wb1, Wb2, kelems);

    // pick largest k-group size that fits (fit-driven; fewer groups = fewer h RMW passes)
    int gs = 0, G = 0;
    for (int cand = K; cand >= 1; --cand) {
        int gc = (K + cand - 1) / cand;
        size_t nbins = (size_t)n * gc;
        size_t nb = (nbins + 4095) / 4096;
        size_t need = fixed_end;
        need = align256(need + nbins * 64);         // cnt (padded 1 bin / 64B)
        need = align256(need + (nbins + 1) * 4);    // row_ptr
        need = align256(need + (nb + 2) * 4);       // bsum
        need += (size_t)cand * (size_t)n * 256;     // y
        if (need <= ws_size) { gs = cand; G = gc; break; }
    }

    if (gs > 0) {
        size_t nbins = (size_t)n * G;
        size_t nb = (nbins + 4095) / 4096;
        off = fixed_end;
        int* cnt     = (int*)(ws + off); off = align256(off + nbins * 64);
        int* row_ptr = (int*)(ws + off); off = align256(off + (nbins + 1) * 4);
        int* bsum    = (int*)(ws + off); off = align256(off + (nb + 2) * 4);
        unsigned* yu = (unsigned*)(ws + off);
        const int gsn = gs * n;

        // CSR build: one return-atomic pass (linear rank write) + scan
        hipLaunchKernelGGL(zero_f32, dim3((int)((nbins * 16 / 4 + 255) / 256) + 1), b256, 0, stream,
                           (float*)cnt, (long)(nbins * 16));
        hipLaunchKernelGGL(hist_rank, dim3((nk + 255) / 256), b256, 0, stream,
                           idx_out, cnt, rank, nk, gsn, n, G);
        hipLaunchKernelGGL(scan_part, dim3((int)nb), b256, 0, stream, cnt, bsum, (int)nbins);
        hipLaunchKernelGGL(scan_bsum, dim3(1), dim3(64), 0, stream, bsum, (int)nb, row_ptr, (int)nbins);
        hipLaunchKernelGGL(scan_final, dim3((int)nb), b256, 0, stream, cnt, bsum, row_ptr, (int)nbins);

        for (int conv = 0; conv < 2; ++conv) {
            const unsigned short* Wb = conv ? Wb2 : Wb1;
            float* st = stats + conv * 512;
            for (int g = 0; g < G; ++g) {
                int ks = min(gs, K - g * gs);
                hipLaunchKernelGGL(gemm_y_slot, dim3((n + 255) / 256, ks), dim3(512), 0, stream,
                                   slabA, Wb + (size_t)g * gs * 16384,
                                   idx_in + (size_t)g * gsn, idx_out + (size_t)g * gsn,
                                   rank + (size_t)g * gsn, row_ptr + (size_t)g * n,
                                   yu, n, g * gsn);
                hipLaunchKernelGGL(reduce_y_grp, dim3(2048), b256, 0, stream,
                                   yu, row_ptr + (size_t)g * n, acc, st,
                                   n, g * gsn, (g > 0) ? 1 : 0, (g == G - 1) ? 1 : 0);
            }
            hipLaunchKernelGGL(bn_finalize, dim3(1), dim3(128), 0, stream, st,
                               conv ? g2 : g1, conv ? b2 : b1, 1.0f / n);
            if (conv == 0)
                hipLaunchKernelGGL(bn_relu_bf16, dim3(gCvt), b256, 0, stream, acc, st, slabA, total);
            else
                hipLaunchKernelGGL(bn_res_relu, dim3(gCvt), b256, 0, stream, acc, st, x, total);
        }
    } else {
        for (int conv = 0; conv < 2; ++conv) {
            const unsigned short* Wb = conv ? Wb2 : Wb1;
            float* st = stats + conv * 512;
            hipLaunchKernelGGL(zero_f32, dim3(gCvt), b256, 0, stream, acc, total);
            hipLaunchKernelGGL(conv_atomic, dim3((n + 255) / 256, K), dim3(512), 0, stream,
                               slabA, Wb, idx_in, idx_out, acc, n);
            hipLaunchKernelGGL(bn_stats, dim3((n + 255) / 256), b256, 0, stream, acc, st, n);
            hipLaunchKernelGGL(bn_finalize, dim3(1), dim3(128), 0, stream, st,
                               conv ? g2 : g1, conv ? b2 : b1, 1.0f / n);
            if (conv == 0)
                hipLaunchKernelGGL(bn_relu_bf16, dim3(gCvt), b256, 0, stream, acc, st, slabA, total);
            else
                hipLaunchKernelGGL(bn_res_relu, dim3(gCvt), b256, 0, stream, acc, st, x, total);
        }
    }
}